// Round 1
// baseline (2143.670 us; speedup 1.0000x reference)
//
#include <hip/hip_runtime.h>
#include <hip/hip_bf16.h>
#include <cstdint>

#define DEV __device__ __forceinline__

// Problem constants (from setup_inputs)
constexpr int Bn   = 8;
constexpr int Nn   = 4096;
constexpr int Mn   = 1024;   // N / STRIDE
constexpr int Kn   = 32;     // NSAMPLE
constexpr int CIN  = 64;
constexpr int CMID = 64;
constexpr int COUT = 128;

// ---------------------------------------------------------------------------
// feats (B, 64, 4096) -> featsT (B, 4096, 64)
// ---------------------------------------------------------------------------
__global__ __launch_bounds__(256) void k_tr(const float* __restrict__ feats,
                                            float* __restrict__ featsT) {
  __shared__ float tile[64][65];
  int b = blockIdx.x >> 6, n0 = (blockIdx.x & 63) * 64;
  int t = threadIdx.x;
  int lane = t & 63, grp = t >> 6;
  for (int r = 0; r < 16; ++r) {
    int c = grp + r * 4;
    tile[c][lane] = feats[((size_t)b * 64 + c) * 4096 + n0 + lane];
  }
  __syncthreads();
  for (int r = 0; r < 16; ++r) {
    int n = grp + r * 4;
    featsT[((size_t)b * 4096 + n0 + n) * 64 + lane] = tile[lane][n];
  }
}

// ---------------------------------------------------------------------------
// Farthest point sampling. 1 block per batch. Faithful fp32 (no FMA) since
// argmax decisions are chaotic. Emits sample_idx and sampled coords (output 0).
// ---------------------------------------------------------------------------
DEV void red_argmax(float& bv, uint32_t& bi) {
#pragma unroll
  for (int off = 1; off < 64; off <<= 1) {
    float    ov = __shfl_xor(bv, off, 64);
    uint32_t oi = __shfl_xor(bi, off, 64);
    if (ov > bv || (ov == bv && oi < bi)) { bv = ov; bi = oi; }
  }
}

__global__ __launch_bounds__(256) void k_fps(const float* __restrict__ coords,
                                             uint32_t* __restrict__ sidx,
                                             float* __restrict__ outc) {
  const int b = blockIdx.x, t = threadIdx.x;
  __shared__ float sx[Nn], sy[Nn], sz[Nn];
  __shared__ float s_rv[2][4];
  __shared__ uint32_t s_ri[2][4];
  __shared__ float s_mean[3];

  const float* cb = coords + (size_t)b * Nn * 3;
  for (int i = t; i < Nn; i += 256) {
    sx[i] = cb[3 * i]; sy[i] = cb[3 * i + 1]; sz[i] = cb[3 * i + 2];
  }
  __syncthreads();
  if (t == 0) {  // sequential in-order fp32 mean (numpy reduce order)
    float ax = 0.f, ay = 0.f, az = 0.f;
    for (int i = 0; i < Nn; ++i) {
      ax = __fadd_rn(ax, sx[i]); ay = __fadd_rn(ay, sy[i]); az = __fadd_rn(az, sz[i]);
    }
    s_mean[0] = __fdiv_rn(ax, 4096.f);
    s_mean[1] = __fdiv_rn(ay, 4096.f);
    s_mean[2] = __fdiv_rn(az, 4096.f);
  }
  __syncthreads();

  float px[16], py[16], pz[16], md[16];
#pragma unroll
  for (int j = 0; j < 16; ++j) {
    int i = t + 256 * j;
    px[j] = sx[i]; py[j] = sy[i]; pz[j] = sz[i];
    md[j] = __builtin_inff();
  }
  float mx = s_mean[0], my = s_mean[1], mz = s_mean[2];

  // initial farthest = argmax dist-to-mean (first-index tie-break)
  float bv = -1.f; uint32_t bi = 0u;
#pragma unroll
  for (int j = 0; j < 16; ++j) {
    float dx = __fsub_rn(px[j], mx), dy = __fsub_rn(py[j], my), dz = __fsub_rn(pz[j], mz);
    float d  = __fadd_rn(__fadd_rn(__fmul_rn(dx, dx), __fmul_rn(dy, dy)), __fmul_rn(dz, dz));
    if (d > bv) { bv = d; bi = (uint32_t)(t + 256 * j); }  // ascending idx scan
  }
  red_argmax(bv, bi);
  const int wv = t >> 6, ln = t & 63;
  if (ln == 0) { s_rv[0][wv] = bv; s_ri[0][wv] = bi; }
  __syncthreads();
  float fv = s_rv[0][0]; uint32_t fi = s_ri[0][0];
#pragma unroll
  for (int w = 1; w < 4; ++w) {
    float v2 = s_rv[0][w]; uint32_t i2 = s_ri[0][w];
    if (v2 > fv || (v2 == fv && i2 < fi)) { fv = v2; fi = i2; }
  }
  uint32_t far = fi;

  for (int it = 0; it < Mn; ++it) {
    if (t == 0) {
      sidx[b * Mn + it] = far;
      outc[(size_t)(b * Mn + it) * 3 + 0] = sx[far];
      outc[(size_t)(b * Mn + it) * 3 + 1] = sy[far];
      outc[(size_t)(b * Mn + it) * 3 + 2] = sz[far];
    }
    if (it == Mn - 1) break;
    float cx = sx[far], cy = sy[far], cz = sz[far];
    float bv2 = -1.f; uint32_t bi2 = 0u;
#pragma unroll
    for (int j = 0; j < 16; ++j) {
      float dx = __fsub_rn(px[j], cx), dy = __fsub_rn(py[j], cy), dz = __fsub_rn(pz[j], cz);
      float d  = __fadd_rn(__fadd_rn(__fmul_rn(dx, dx), __fmul_rn(dy, dy)), __fmul_rn(dz, dz));
      float m2 = fminf(md[j], d);
      md[j] = m2;
      if (m2 > bv2) { bv2 = m2; bi2 = (uint32_t)(t + 256 * j); }
    }
    red_argmax(bv2, bi2);
    int par = (it & 1) ^ 1;  // double-buffered slots -> single barrier per iter
    if (ln == 0) { s_rv[par][wv] = bv2; s_ri[par][wv] = bi2; }
    __syncthreads();
    float fv2 = s_rv[par][0]; uint32_t fi2 = s_ri[par][0];
#pragma unroll
    for (int w = 1; w < 4; ++w) {
      float v2 = s_rv[par][w]; uint32_t i2 = s_ri[par][w];
      if (v2 > fv2 || (v2 == fv2 && i2 < fi2)) { fv2 = v2; fi2 = i2; }
    }
    far = fi2;
  }
}

// ---------------------------------------------------------------------------
// 32-NN per query (== reference ball_query+knn fallback) + density weights.
// 1 block per query. Compact within-radius candidates, bitonic-sort
// (d2_bits<<32)|idx keys ascending; fallback to full sort if <32 in radius.
// ---------------------------------------------------------------------------
__global__ __launch_bounds__(256) void k_knn(const float* __restrict__ coords,
                                             const uint32_t* __restrict__ sidx,
                                             uint32_t* __restrict__ gidx,
                                             float* __restrict__ wts) {
  const int q = blockIdx.x;
  const int b = q >> 10;
  const int t = threadIdx.x;
  __shared__ uint64_t keys[4096];
  __shared__ int s_cnt;
  __shared__ float s_q[4];
  __shared__ float gx[32], gy[32], gz[32], g2[32];
  __shared__ float dmat[32 * 33];
  __shared__ float kth[32];
  __shared__ float s_raw[32];
  __shared__ float s_sum;

  if (t == 0) {
    s_cnt = 0;
    uint32_t si = sidx[q];
    const float* c = &coords[((size_t)b * Nn + si) * 3];
    s_q[0] = c[0]; s_q[1] = c[1]; s_q[2] = c[2];
  }
  __syncthreads();
  float qx = s_q[0], qy = s_q[1], qz = s_q[2];
  float q2 = __fadd_rn(__fadd_rn(__fmul_rn(qx, qx), __fmul_rn(qy, qy)), __fmul_rn(qz, qz));
  const float* cb = coords + (size_t)b * Nn * 3;

  // phase 1: compact candidates with d2 <= r^2 (selection itself is pure kNN,
  // so the threshold only needs to over-cover the 32 nearest when cnt>=32)
  for (int j = 0; j < 16; ++j) {
    int i = t + 256 * j;
    float cx = cb[3 * i], cy = cb[3 * i + 1], cz = cb[3 * i + 2];
    float c2  = __fadd_rn(__fadd_rn(__fmul_rn(cx, cx), __fmul_rn(cy, cy)), __fmul_rn(cz, cz));
    float dot = __fadd_rn(__fadd_rn(__fmul_rn(qx, cx), __fmul_rn(qy, cy)), __fmul_rn(qz, cz));
    float d2  = __fsub_rn(__fadd_rn(q2, c2), __fmul_rn(2.f, dot));
    float d2c = fmaxf(d2, 1e-12f);
    bool pred = (d2c <= 0.04f);
    unsigned long long mk = __ballot(pred);
    int base = 0;
    if ((t & 63) == 0) base = mk ? atomicAdd(&s_cnt, (int)__popcll(mk)) : 0;
    base = __shfl(base, 0, 64);
    if (pred) {
      int pos = base + (int)__popcll(mk & ((1ull << (t & 63)) - 1ull));
      keys[pos] = ((uint64_t)__float_as_uint(d2c) << 32) | (uint32_t)i;
    }
  }
  __syncthreads();
  int cnt = s_cnt;
  if (cnt < 32) {  // rare (boundary/corner queries): sort everything
    for (int j = 0; j < 16; ++j) {
      int i = t + 256 * j;
      float cx = cb[3 * i], cy = cb[3 * i + 1], cz = cb[3 * i + 2];
      float c2  = __fadd_rn(__fadd_rn(__fmul_rn(cx, cx), __fmul_rn(cy, cy)), __fmul_rn(cz, cz));
      float dot = __fadd_rn(__fadd_rn(__fmul_rn(qx, cx), __fmul_rn(qy, cy)), __fmul_rn(qz, cz));
      float d2  = __fsub_rn(__fadd_rn(q2, c2), __fmul_rn(2.f, dot));
      float d2c = fmaxf(d2, 1e-12f);
      keys[i] = ((uint64_t)__float_as_uint(d2c) << 32) | (uint32_t)i;
    }
    cnt = 4096;
  }
  int S = 64;
  while (S < cnt) S <<= 1;
  for (int i = t; i < S; i += 256)
    if (i >= cnt) keys[i] = 0xffffffffffffffffull;
  __syncthreads();

  for (int k = 2; k <= S; k <<= 1) {
    for (int j = k >> 1; j > 0; j >>= 1) {
      for (int i = t; i < S; i += 256) {
        int l = i ^ j;
        if (l > i) {
          uint64_t a = keys[i], c = keys[l];
          bool up = ((i & k) == 0);
          if (up ? (a > c) : (a < c)) { keys[i] = c; keys[l] = a; }
        }
      }
      __syncthreads();
    }
  }

  if (t < 32) {
    uint32_t gi = (uint32_t)(keys[t] & 0xffffffffu);
    gidx[(size_t)q * 32 + t] = gi;
    const float* c = &coords[((size_t)b * Nn + gi) * 3];
    float x = c[0], y = c[1], z = c[2];
    gx[t] = x; gy[t] = y; gz[t] = z;
    g2[t] = __fadd_rn(__fadd_rn(__fmul_rn(x, x), __fmul_rn(y, y)), __fmul_rn(z, z));
  }
  __syncthreads();
  // pairwise distances among the 32 grouped points
  for (int p = t; p < 1024; p += 256) {
    int i = p >> 5, jj = p & 31;
    float dot = __fadd_rn(__fadd_rn(__fmul_rn(gx[i], gx[jj]), __fmul_rn(gy[i], gy[jj])),
                          __fmul_rn(gz[i], gz[jj]));
    float d2 = __fsub_rn(__fadd_rn(g2[i], g2[jj]), __fmul_rn(2.f, dot));
    float dd = sqrtf(fmaxf(d2, 1e-12f));
    if (i == jj) dd = __builtin_inff();
    dmat[i * 33 + jj] = dd;
  }
  __syncthreads();
  // 16th-smallest value per row via rank (total order on (value, idx))
  for (int p = t; p < 1024; p += 256) {
    int i = p >> 5, jj = p & 31;
    float v = dmat[i * 33 + jj];
    int r = 0;
    for (int c = 0; c < 32; ++c) {
      float u = dmat[i * 33 + c];
      r += (u < v) || (u == v && c < jj);
    }
    if (r == 15) kth[i] = v;
  }
  __syncthreads();
  if (t < 32) { float x = fmaxf(kth[t], 1e-8f); s_raw[t] = x * x * x; }
  __syncthreads();
  if (t == 0) {
    float s = 0.f;
    for (int i2 = 0; i2 < 32; ++i2) s += s_raw[i2];
    s_sum = fmaxf(s, 1e-8f);
  }
  __syncthreads();
  if (t < 32) wts[(size_t)q * 32 + t] = s_raw[t] / s_sum;
}

// ---------------------------------------------------------------------------
// Shared helpers for the conv pipeline (tile = 4 queries x 32 neighbors)
// ---------------------------------------------------------------------------
DEV void build_x(const float* __restrict__ coords, const float* __restrict__ featsT,
                 const uint32_t* __restrict__ sidx, const uint32_t* __restrict__ gidx,
                 const float* __restrict__ W0, int b, int m0, int t,
                 float* xs /*[67*129]*/, float* w0s /*[64*67]*/,
                 uint32_t* s_gi /*[128]*/, float* s_qc /*[12]*/) {
  for (int i = t; i < 64 * 67; i += 256) w0s[i] = W0[i];
  if (t < 128) {
    s_gi[t] = gidx[((size_t)(b * Mn + m0)) * 32 + t];
  } else if (t < 132) {
    int mm = t - 128;
    uint32_t si = sidx[b * Mn + m0 + mm];
    const float* c = &coords[((size_t)b * Nn + si) * 3];
    s_qc[mm * 3 + 0] = c[0]; s_qc[mm * 3 + 1] = c[1]; s_qc[mm * 3 + 2] = c[2];
  }
  __syncthreads();
  if (t < 128) {
    int mm = t >> 5;
    const float* c = &coords[((size_t)b * Nn + s_gi[t]) * 3];
    xs[0 * 129 + t] = (c[0] - s_qc[mm * 3 + 0]) / 0.2f;
    xs[1 * 129 + t] = (c[1] - s_qc[mm * 3 + 1]) / 0.2f;
    xs[2 * 129 + t] = (c[2] - s_qc[mm * 3 + 2]) / 0.2f;
  }
  {
    int c = t & 63, k0 = t >> 6;
    for (int r2 = 0; r2 < 32; ++r2) {
      int kk = k0 + 4 * r2;
      xs[(size_t)(3 + c) * 129 + kk] = featsT[((size_t)b * Nn + s_gi[kk]) * 64 + c];
    }
  }
  __syncthreads();
}

DEV void conv1_acc(const float* xs, const float* w0s, int o, int kg, float acc[32]) {
#pragma unroll
  for (int k = 0; k < 32; ++k) acc[k] = 0.f;
  for (int c = 0; c < 67; ++c) {
    float w = w0s[o * 67 + c];
    const float* xr = &xs[(size_t)c * 129 + kg * 32];
#pragma unroll
    for (int k = 0; k < 32; ++k) acc[k] = fmaf(w, xr[k], acc[k]);
  }
}

// stats layout (floats): [0,64) s0 | [64,128) q0 | [128,256) s1 | [256,384) q1
// | [384,512) ss | [512,640) qs | [640) a0 | [704) c0 | [768) a1 | [896) c1
// | [1024) as | [1152) cs
__global__ __launch_bounds__(256) void k_conv1(const float* __restrict__ coords,
                                               const float* __restrict__ featsT,
                                               const uint32_t* __restrict__ sidx,
                                               const uint32_t* __restrict__ gidx,
                                               const float* __restrict__ W0,
                                               float* __restrict__ stats) {
  __shared__ float xs[67 * 129];
  __shared__ float w0s[64 * 67];
  __shared__ uint32_t s_gi[128];
  __shared__ float s_qc[12];
  __shared__ float ssum[64], ssq[64];
  int blk = blockIdx.x, t = threadIdx.x;
  int b = blk >> 8, m0 = (blk & 255) << 2;
  if (t < 64) { ssum[t] = 0.f; ssq[t] = 0.f; }
  build_x(coords, featsT, sidx, gidx, W0, b, m0, t, xs, w0s, s_gi, s_qc);
  int o = t & 63, kg = t >> 6;
  float acc[32];
  conv1_acc(xs, w0s, o, kg, acc);
  float s = 0.f, sq = 0.f;
#pragma unroll
  for (int k = 0; k < 32; ++k) { s += acc[k]; sq = fmaf(acc[k], acc[k], sq); }
  atomicAdd(&ssum[o], s); atomicAdd(&ssq[o], sq);
  __syncthreads();
  if (t < 64) { atomicAdd(&stats[t], ssum[t]); atomicAdd(&stats[64 + t], ssq[t]); }
}

__global__ void k_fin0(float* stats, const float* g0, const float* b0) {
  int t = threadIdx.x;
  if (t >= 64) return;
  float mu  = stats[t] * (1.f / 262144.f);
  float var = stats[64 + t] * (1.f / 262144.f) - mu * mu;
  float a = g0[t] / sqrtf(var + 1e-5f);
  stats[640 + t] = a;
  stats[704 + t] = b0[t] - mu * a;
}

__global__ __launch_bounds__(256) void k_conv2(const float* __restrict__ coords,
                                               const float* __restrict__ featsT,
                                               const uint32_t* __restrict__ sidx,
                                               const uint32_t* __restrict__ gidx,
                                               const float* __restrict__ W0,
                                               const float* __restrict__ W1,
                                               float* __restrict__ stats) {
  __shared__ float smU[12931];  // xs[67*129]+w0s[64*67]  |  hs[64*129]+w1sT[64*65]
  __shared__ uint32_t s_gi[128];
  __shared__ float s_qc[12];
  __shared__ float ssum[128], ssq[128];
  float* xs = smU; float* w0s = smU + 67 * 129;
  float* hs = smU; float* w1sT = smU + 64 * 129;
  int blk = blockIdx.x, t = threadIdx.x;
  int b = blk >> 8, m0 = (blk & 255) << 2;
  if (t < 128) { ssum[t] = 0.f; ssq[t] = 0.f; }
  build_x(coords, featsT, sidx, gidx, W0, b, m0, t, xs, w0s, s_gi, s_qc);
  int o = t & 63, kg = t >> 6;
  float acc[32];
  conv1_acc(xs, w0s, o, kg, acc);
  float a0 = stats[640 + o], c0 = stats[704 + o];
  __syncthreads();  // conv1 reads done; smU may be repurposed
#pragma unroll
  for (int k = 0; k < 32; ++k)
    hs[(size_t)o * 129 + kg * 32 + k] = fmaxf(fmaf(a0, acc[k], c0), 0.f);
  for (int p = 0; p < 2; ++p) {
    __syncthreads();
    for (int i = t; i < 4096; i += 256) {
      int oo = i >> 6, cc = i & 63;
      w1sT[cc * 65 + oo] = W1[(size_t)(64 * p + oo) * 64 + cc];
    }
    __syncthreads();
    float acc2[32];
#pragma unroll
    for (int k = 0; k < 32; ++k) acc2[k] = 0.f;
    for (int c = 0; c < 64; ++c) {
      float ww = w1sT[c * 65 + o];
      const float* hr = &hs[(size_t)c * 129 + kg * 32];
#pragma unroll
      for (int k = 0; k < 32; ++k) acc2[k] = fmaf(ww, hr[k], acc2[k]);
    }
    float s = 0.f, sq = 0.f;
#pragma unroll
    for (int k = 0; k < 32; ++k) { s += acc2[k]; sq = fmaf(acc2[k], acc2[k], sq); }
    atomicAdd(&ssum[o + 64 * p], s); atomicAdd(&ssq[o + 64 * p], sq);
  }
  __syncthreads();
  if (t < 128) { atomicAdd(&stats[128 + t], ssum[t]); atomicAdd(&stats[256 + t], ssq[t]); }
}

__global__ __launch_bounds__(256) void k_skip(const float* __restrict__ featsT,
                                              const uint32_t* __restrict__ sidx,
                                              const float* __restrict__ Ws,
                                              float* __restrict__ ys,
                                              float* __restrict__ stats) {
  __shared__ float fin[64 * 65];
  __shared__ float wssT[64 * 129];
  __shared__ uint32_t s_si[64];
  __shared__ float ssum[128], ssq[128];
  int blk = blockIdx.x, t = threadIdx.x;
  int b = blk >> 4, m0 = (blk & 15) * 64;
  if (t < 64) s_si[t] = sidx[b * Mn + m0 + t];
  if (t < 128) { ssum[t] = 0.f; ssq[t] = 0.f; }
  __syncthreads();
  for (int i = t; i < 64 * 64; i += 256) {
    int mm = i >> 6, c = i & 63;
    fin[mm * 65 + c] = featsT[((size_t)b * Nn + s_si[mm]) * 64 + c];
  }
  for (int i = t; i < 128 * 64; i += 256) {
    int oo = i >> 6, cc = i & 63;
    wssT[cc * 129 + oo] = Ws[(size_t)oo * 64 + cc];
  }
  __syncthreads();
  int o = t & 127, mh = t >> 7;
  float s = 0.f, sq = 0.f;
  for (int mm = mh * 32; mm < mh * 32 + 32; ++mm) {
    float acc = 0.f;
    for (int c = 0; c < 64; ++c) acc = fmaf(wssT[c * 129 + o], fin[mm * 65 + c], acc);
    ys[((size_t)(b * Mn + m0 + mm)) * 128 + o] = acc;
    s += acc; sq = fmaf(acc, acc, sq);
  }
  atomicAdd(&ssum[o], s); atomicAdd(&ssq[o], sq);
  __syncthreads();
  if (t < 128) { atomicAdd(&stats[384 + t], ssum[t]); atomicAdd(&stats[512 + t], ssq[t]); }
}

__global__ void k_fin1(float* stats, const float* g1, const float* b1,
                       const float* gs, const float* bs) {
  int t = threadIdx.x;
  if (t >= 128) return;
  float mu  = stats[128 + t] * (1.f / 262144.f);
  float var = stats[256 + t] * (1.f / 262144.f) - mu * mu;
  float a = g1[t] / sqrtf(var + 1e-5f);
  stats[768 + t] = a;
  stats[896 + t] = b1[t] - mu * a;
  float mus  = stats[384 + t] * (1.f / 8192.f);
  float vars = stats[512 + t] * (1.f / 8192.f) - mus * mus;
  float as = gs[t] / sqrtf(vars + 1e-5f);
  stats[1024 + t] = as;
  stats[1152 + t] = bs[t] - mus * as;
}

__global__ __launch_bounds__(256) void k_out(const float* __restrict__ coords,
                                             const float* __restrict__ featsT,
                                             const uint32_t* __restrict__ sidx,
                                             const uint32_t* __restrict__ gidx,
                                             const float* __restrict__ W0,
                                             const float* __restrict__ W1,
                                             const float* __restrict__ wts,
                                             const float* __restrict__ ys,
                                             const float* __restrict__ stats,
                                             float* __restrict__ out_feat) {
  __shared__ float smU[12931];
  __shared__ uint32_t s_gi[128];
  __shared__ float s_qc[12];
  __shared__ float sw[132];
  __shared__ float red[128 * 5];
  float* xs = smU; float* w0s = smU + 67 * 129;
  float* hs = smU; float* w1sT = smU + 64 * 129;
  int blk = blockIdx.x, t = threadIdx.x;
  int b = blk >> 8, m0 = (blk & 255) << 2;
  build_x(coords, featsT, sidx, gidx, W0, b, m0, t, xs, w0s, s_gi, s_qc);
  if (t < 128) sw[(t >> 5) * 33 + (t & 31)] = wts[((size_t)(b * Mn + m0)) * 32 + t];
  int o = t & 63, kg = t >> 6;
  float acc[32];
  conv1_acc(xs, w0s, o, kg, acc);
  float a0 = stats[640 + o], c0 = stats[704 + o];
  __syncthreads();
#pragma unroll
  for (int k = 0; k < 32; ++k)
    hs[(size_t)o * 129 + kg * 32 + k] = fmaxf(fmaf(a0, acc[k], c0), 0.f);
  for (int p = 0; p < 2; ++p) {
    __syncthreads();
    for (int i = t; i < 4096; i += 256) {
      int oo = i >> 6, cc = i & 63;
      w1sT[cc * 65 + oo] = W1[(size_t)(64 * p + oo) * 64 + cc];
    }
    __syncthreads();
    float acc2[32];
#pragma unroll
    for (int k = 0; k < 32; ++k) acc2[k] = 0.f;
    for (int c = 0; c < 64; ++c) {
      float ww = w1sT[c * 65 + o];
      const float* hr = &hs[(size_t)c * 129 + kg * 32];
#pragma unroll
      for (int k = 0; k < 32; ++k) acc2[k] = fmaf(ww, hr[k], acc2[k]);
    }
    int o2 = o + 64 * p;
    float a1 = stats[768 + o2], c1 = stats[896 + o2];
    float as = stats[1024 + o2], cs = stats[1152 + o2];
    float r = 0.f;
#pragma unroll
    for (int k = 0; k < 32; ++k) {
      float msg = fmaxf(fmaf(a1, acc2[k], c1), 0.f);
      r = fmaf(msg, sw[kg * 33 + k], r);
    }
    float ysv = ys[((size_t)(b * Mn + m0 + kg)) * 128 + o2];
    red[o2 * 5 + kg] = fmaxf(r + fmaf(as, ysv, cs), 0.f);
  }
  __syncthreads();
  for (int e = t; e < 512; e += 256) {
    int oo = e >> 2, mm = e & 3;
    out_feat[(size_t)b * 131072 + (size_t)oo * 1024 + m0 + mm] = red[oo * 5 + mm];
  }
}

// ---------------------------------------------------------------------------
extern "C" void kernel_launch(void* const* d_in, const int* in_sizes, int n_in,
                              void* d_out, int out_size, void* d_ws, size_t ws_size,
                              hipStream_t stream) {
  const float* coords = (const float*)d_in[0];
  const float* feats  = (const float*)d_in[1];
  const float* W0 = (const float*)d_in[2];
  const float* g0 = (const float*)d_in[3];
  const float* b0 = (const float*)d_in[4];
  const float* W1 = (const float*)d_in[5];
  const float* g1 = (const float*)d_in[6];
  const float* b1 = (const float*)d_in[7];
  const float* Ws = (const float*)d_in[8];
  const float* gs = (const float*)d_in[9];
  const float* bs = (const float*)d_in[10];

  float* out_coords = (float*)d_out;
  float* out_feat   = out_coords + (size_t)Bn * Mn * 3;

  char* w = (char*)d_ws;
  float*    featsT = (float*)w;    w += (size_t)Bn * Nn * CIN * 4;   // 8 MB
  uint32_t* sidx   = (uint32_t*)w; w += (size_t)Bn * Mn * 4;
  uint32_t* gidx   = (uint32_t*)w; w += (size_t)Bn * Mn * Kn * 4;
  float*    wts    = (float*)w;    w += (size_t)Bn * Mn * Kn * 4;
  float*    ys     = (float*)w;    w += (size_t)Bn * Mn * COUT * 4;  // 4 MB
  float*    stats  = (float*)w;    w += 1280 * 4;
  // total ~14.7 MB of d_ws

  hipMemsetAsync(stats, 0, 640 * 4, stream);
  hipLaunchKernelGGL(k_tr,    dim3(512),  dim3(256), 0, stream, feats, featsT);
  hipLaunchKernelGGL(k_fps,   dim3(8),    dim3(256), 0, stream, coords, sidx, out_coords);
  hipLaunchKernelGGL(k_knn,   dim3(8192), dim3(256), 0, stream, coords, sidx, gidx, wts);
  hipLaunchKernelGGL(k_conv1, dim3(2048), dim3(256), 0, stream, coords, featsT, sidx, gidx, W0, stats);
  hipLaunchKernelGGL(k_skip,  dim3(128),  dim3(256), 0, stream, featsT, sidx, Ws, ys, stats);
  hipLaunchKernelGGL(k_fin0,  dim3(1),    dim3(64),  0, stream, stats, g0, b0);
  hipLaunchKernelGGL(k_conv2, dim3(2048), dim3(256), 0, stream, coords, featsT, sidx, gidx, W0, W1, stats);
  hipLaunchKernelGGL(k_fin1,  dim3(1),    dim3(128), 0, stream, stats, g1, b1, gs, bs);
  hipLaunchKernelGGL(k_out,   dim3(2048), dim3(256), 0, stream, coords, featsT, sidx, gidx, W0, W1, wts, ys, stats, out_feat);
}

// Round 2
// 1336.980 us; speedup vs baseline: 1.6034x; 1.6034x over previous
//
#include <hip/hip_runtime.h>
#include <hip/hip_bf16.h>
#include <cstdint>

#define DEV __device__ __forceinline__

// Problem constants (from setup_inputs)
constexpr int Bn   = 8;
constexpr int Nn   = 4096;
constexpr int Mn   = 1024;   // N / STRIDE
constexpr int Kn   = 32;     // NSAMPLE
constexpr int CIN  = 64;
constexpr int COUT = 128;

// ---------------------------------------------------------------------------
// feats (B, 64, 4096) -> featsT (B, 4096, 64)
// ---------------------------------------------------------------------------
__global__ __launch_bounds__(256) void k_tr(const float* __restrict__ feats,
                                            float* __restrict__ featsT) {
  __shared__ float tile[64][65];
  int b = blockIdx.x >> 6, n0 = (blockIdx.x & 63) * 64;
  int t = threadIdx.x;
  int lane = t & 63, grp = t >> 6;
  for (int r = 0; r < 16; ++r) {
    int c = grp + r * 4;
    tile[c][lane] = feats[((size_t)b * 64 + c) * 4096 + n0 + lane];
  }
  __syncthreads();
  for (int r = 0; r < 16; ++r) {
    int n = grp + r * 4;
    featsT[((size_t)b * 4096 + n0 + n) * 64 + lane] = tile[lane][n];
  }
}

// ---------------------------------------------------------------------------
// FPS. 1 block/batch. Decision arithmetic bit-identical to numpy ref
// (no FMA contraction, first-index tie-break). Fast path: DPP wave argmax.
// ---------------------------------------------------------------------------
DEV unsigned long long wave_max_key(unsigned long long key) {
#if __has_builtin(__builtin_amdgcn_update_dpp)
#define DPP_STEP(CTRL, RMASK)                                                          \
  {                                                                                    \
    unsigned int lo2 = (unsigned int)__builtin_amdgcn_update_dpp(                      \
        0, (int)(unsigned int)key, CTRL, RMASK, 0xf, false);                           \
    unsigned int hi2 = (unsigned int)__builtin_amdgcn_update_dpp(                      \
        0, (int)(unsigned int)(key >> 32), CTRL, RMASK, 0xf, false);                   \
    unsigned long long k2 = ((unsigned long long)hi2 << 32) | lo2;                     \
    if (k2 > key) key = k2;                                                            \
  }
  DPP_STEP(0x111, 0xf)  // row_shr:1
  DPP_STEP(0x112, 0xf)  // row_shr:2
  DPP_STEP(0x114, 0xf)  // row_shr:4
  DPP_STEP(0x118, 0xf)  // row_shr:8
  DPP_STEP(0x142, 0xa)  // row_bcast:15 rows 1,3
  DPP_STEP(0x143, 0xc)  // row_bcast:31 rows 2,3
#undef DPP_STEP
#else
  for (int off = 1; off < 64; off <<= 1) {
    unsigned int lo2 = __shfl_xor((unsigned int)key, off, 64);
    unsigned int hi2 = __shfl_xor((unsigned int)(key >> 32), off, 64);
    unsigned long long k2 = ((unsigned long long)hi2 << 32) | lo2;
    if (k2 > key) key = k2;
  }
#endif
  return key;  // lane 63 holds the wave max
}

// key = (f32bits(value) << 32) | (0xFFFFFFFF - index): max key == (max value,
// tie -> min index). Values are squared distances >= 0 so bit order == fp order.
DEV uint32_t block_argmax16(const float v[16], int t,
                            unsigned long long (*part)[4], int slot) {
  // in-register tree (tie -> left == smaller j == smaller index)
  float v8[8]; int j8[8];
#pragma unroll
  for (int i = 0; i < 8; ++i) {
    bool r = v[2 * i + 1] > v[2 * i];
    v8[i] = r ? v[2 * i + 1] : v[2 * i];
    j8[i] = r ? 2 * i + 1 : 2 * i;
  }
  float v4[4]; int j4[4];
#pragma unroll
  for (int i = 0; i < 4; ++i) {
    bool r = v8[2 * i + 1] > v8[2 * i];
    v4[i] = r ? v8[2 * i + 1] : v8[2 * i];
    j4[i] = r ? j8[2 * i + 1] : j8[2 * i];
  }
  float v2[2]; int j2[2];
#pragma unroll
  for (int i = 0; i < 2; ++i) {
    bool r = v4[2 * i + 1] > v4[2 * i];
    v2[i] = r ? v4[2 * i + 1] : v4[2 * i];
    j2[i] = r ? j4[2 * i + 1] : j4[2 * i];
  }
  bool r = v2[1] > v2[0];
  float bv = r ? v2[1] : v2[0];
  int bj = r ? j2[1] : j2[0];

  uint32_t idx = (uint32_t)t + ((uint32_t)bj << 8);  // t + 256*bj
  unsigned long long key =
      ((unsigned long long)__float_as_uint(bv) << 32) | (0xFFFFFFFFu - idx);
  key = wave_max_key(key);
  if ((t & 63) == 63) part[slot][t >> 6] = key;
  __syncthreads();
  unsigned long long p0 = part[slot][0], p1 = part[slot][1];
  unsigned long long p2 = part[slot][2], p3 = part[slot][3];
  unsigned long long a = p0 > p1 ? p0 : p1;
  unsigned long long b2 = p2 > p3 ? p2 : p3;
  unsigned long long k = a > b2 ? a : b2;
  return 0xFFFFFFFFu - (uint32_t)k;
}

__global__ __launch_bounds__(256) void k_fps(const float* __restrict__ coords,
                                             uint32_t* __restrict__ sidx,
                                             float* __restrict__ outc) {
  const int b = blockIdx.x, t = threadIdx.x;
  __shared__ float4 sp[Nn];                      // xyz packed, 64 KB
  __shared__ unsigned long long part[2][4];
  __shared__ uint32_t farl[Mn];
  __shared__ float s_mean[4];

  const float* cb = coords + (size_t)b * Nn * 3;
  for (int i = t; i < Nn; i += 256)
    sp[i] = make_float4(cb[3 * i], cb[3 * i + 1], cb[3 * i + 2], 0.f);
  __syncthreads();
  if (t == 0) {  // sequential in-order fp32 mean (matched ref last round)
    float ax = 0.f, ay = 0.f, az = 0.f;
    for (int i = 0; i < Nn; ++i) {
      float4 c = sp[i];
      ax = __fadd_rn(ax, c.x); ay = __fadd_rn(ay, c.y); az = __fadd_rn(az, c.z);
    }
    s_mean[0] = __fdiv_rn(ax, 4096.f);
    s_mean[1] = __fdiv_rn(ay, 4096.f);
    s_mean[2] = __fdiv_rn(az, 4096.f);
  }
  __syncthreads();

  float px[16], py[16], pz[16], md[16], tv[16];
#pragma unroll
  for (int j = 0; j < 16; ++j) {
    float4 c = sp[t + 256 * j];
    px[j] = c.x; py[j] = c.y; pz[j] = c.z;
    md[j] = __builtin_inff();
  }
  float mx = s_mean[0], my = s_mean[1], mz = s_mean[2];
#pragma unroll
  for (int j = 0; j < 16; ++j) {
    float dx = __fsub_rn(px[j], mx), dy = __fsub_rn(py[j], my), dz = __fsub_rn(pz[j], mz);
    tv[j] = __fadd_rn(__fadd_rn(__fmul_rn(dx, dx), __fmul_rn(dy, dy)), __fmul_rn(dz, dz));
  }
  uint32_t far = block_argmax16(tv, t, part, 0);

  for (int it = 0; it < Mn; ++it) {
    if (t == 0) farl[it] = far;
    if (it == Mn - 1) break;
    float4 c = sp[far];
#pragma unroll
    for (int j = 0; j < 16; ++j) {
      float dx = __fsub_rn(px[j], c.x), dy = __fsub_rn(py[j], c.y), dz = __fsub_rn(pz[j], c.z);
      float d = __fadd_rn(__fadd_rn(__fmul_rn(dx, dx), __fmul_rn(dy, dy)), __fmul_rn(dz, dz));
      float m = fminf(md[j], d);
      md[j] = m;
      tv[j] = m;
    }
    far = block_argmax16(tv, t, part, (it & 1) ^ 1);
  }
  __syncthreads();
  for (int i = t; i < Mn; i += 256) {
    uint32_t f = farl[i];
    sidx[b * Mn + i] = f;
    float4 c = sp[f];
    outc[(size_t)(b * Mn + i) * 3 + 0] = c.x;
    outc[(size_t)(b * Mn + i) * 3 + 1] = c.y;
    outc[(size_t)(b * Mn + i) * 3 + 2] = c.z;
  }
}

// ---------------------------------------------------------------------------
// 32-NN per query (== reference ball_query+knn fallback) + density weights.
// Compact within-radius candidates, rank-select 32 smallest (d2,idx) keys.
// Radius expansion 0.04 -> 0.16 -> inf if fewer than 32 candidates.
// ---------------------------------------------------------------------------
__global__ __launch_bounds__(256) void k_knn(const float* __restrict__ coords,
                                             const uint32_t* __restrict__ sidx,
                                             uint32_t* __restrict__ gidx,
                                             float* __restrict__ wts) {
  const int q = blockIdx.x;
  const int b = q >> 10;
  const int t = threadIdx.x;
  __shared__ unsigned long long keys[Nn + 2];
  __shared__ int s_cnt;
  __shared__ float s_q[4];
  __shared__ uint32_t s_sel[32];
  __shared__ float gx[32], gy[32], gz[32], g2[32];
  __shared__ float dmat[32 * 33];
  __shared__ float kth[32];
  __shared__ float s_raw[32];
  __shared__ float s_sum;

  if (t == 0) {
    uint32_t si = sidx[q];
    const float* c = &coords[((size_t)b * Nn + si) * 3];
    s_q[0] = c[0]; s_q[1] = c[1]; s_q[2] = c[2];
  }
  __syncthreads();
  float qx = s_q[0], qy = s_q[1], qz = s_q[2];
  float q2 = __fadd_rn(__fadd_rn(__fmul_rn(qx, qx), __fmul_rn(qy, qy)), __fmul_rn(qz, qz));
  const float* cb = coords + (size_t)b * Nn * 3;

  float thr = 0.04f;
  int cnt = 0;
  while (true) {
    if (t == 0) s_cnt = 0;
    __syncthreads();
    for (int j = 0; j < 16; ++j) {
      int i = t + 256 * j;
      float cx = cb[3 * i], cy = cb[3 * i + 1], cz = cb[3 * i + 2];
      float c2  = __fadd_rn(__fadd_rn(__fmul_rn(cx, cx), __fmul_rn(cy, cy)), __fmul_rn(cz, cz));
      float dot = __fadd_rn(__fadd_rn(__fmul_rn(qx, cx), __fmul_rn(qy, cy)), __fmul_rn(qz, cz));
      float d2  = __fsub_rn(__fadd_rn(q2, c2), __fmul_rn(2.f, dot));
      float d2c = fmaxf(d2, 1e-12f);
      bool pred = (d2c <= thr);
      unsigned long long mk = __ballot(pred);
      int base = 0;
      if ((t & 63) == 0 && mk) base = atomicAdd(&s_cnt, (int)__popcll(mk));
      base = __shfl(base, 0, 64);
      if (pred) {
        int pos = base + (int)__popcll(mk & ((1ull << (t & 63)) - 1ull));
        keys[pos] = ((unsigned long long)__float_as_uint(d2c) << 32) | (uint32_t)i;
      }
    }
    __syncthreads();
    cnt = s_cnt;
    if (cnt >= 32 || thr > 1.f) break;
    thr = (thr < 0.1f) ? 0.16f : 8.f;
    __syncthreads();
  }
  if (t == 0) { keys[cnt] = ~0ull; keys[cnt + 1] = ~0ull; }
  __syncthreads();
  int cnt2 = (cnt + 1) & ~1;
  for (int i = t; i < cnt; i += 256) {
    unsigned long long ki = keys[i];
    int r = 0;
    for (int j2 = 0; j2 < cnt2; j2 += 2) {
      unsigned long long a = keys[j2], c2 = keys[j2 + 1];
      r += (a < ki) + (c2 < ki);
    }
    if (r < 32) s_sel[r] = (uint32_t)ki;
  }
  __syncthreads();

  if (t < 32) {
    uint32_t gi = s_sel[t];
    gidx[(size_t)q * 32 + t] = gi;
    const float* c = &coords[((size_t)b * Nn + gi) * 3];
    float x = c[0], y = c[1], z = c[2];
    gx[t] = x; gy[t] = y; gz[t] = z;
    g2[t] = __fadd_rn(__fadd_rn(__fmul_rn(x, x), __fmul_rn(y, y)), __fmul_rn(z, z));
  }
  __syncthreads();
  for (int p = t; p < 1024; p += 256) {
    int i = p >> 5, jj = p & 31;
    float dot = __fadd_rn(__fadd_rn(__fmul_rn(gx[i], gx[jj]), __fmul_rn(gy[i], gy[jj])),
                          __fmul_rn(gz[i], gz[jj]));
    float d2 = __fsub_rn(__fadd_rn(g2[i], g2[jj]), __fmul_rn(2.f, dot));
    float dd = sqrtf(fmaxf(d2, 1e-12f));
    if (i == jj) dd = __builtin_inff();
    dmat[i * 33 + jj] = dd;
  }
  __syncthreads();
  for (int p = t; p < 1024; p += 256) {
    int i = p >> 5, jj = p & 31;
    float v = dmat[i * 33 + jj];
    int r = 0;
    for (int c = 0; c < 32; ++c) {
      float u = dmat[i * 33 + c];
      r += (u < v) || (u == v && c < jj);
    }
    if (r == 15) kth[i] = v;
  }
  __syncthreads();
  if (t < 32) { float x = fmaxf(kth[t], 1e-8f); s_raw[t] = x * x * x; }
  __syncthreads();
  if (t == 0) {
    float s = 0.f;
    for (int i2 = 0; i2 < 32; ++i2) s += s_raw[i2];
    s_sum = fmaxf(s, 1e-8f);
  }
  __syncthreads();
  if (t < 32) wts[(size_t)q * 32 + t] = s_raw[t] / s_sum;
}

// ---------------------------------------------------------------------------
// Conv pipeline. Tile = 4 queries x 32 neighbors (GEMM k-dim = 128).
// Thread tile: 4 outputs x 8 k (o0 = (t&15)*4, k0 = (t>>4)*8).
// LDS: xs[67][132] (row 0..2 = rel, 3..66 = feats), w0sT[67][68] (W0^T).
// ---------------------------------------------------------------------------
constexpr int XST = 132;
constexpr int WST = 68;

DEV void build_x(const float* __restrict__ coords, const float* __restrict__ featsT,
                 const uint32_t* __restrict__ sidx, const uint32_t* __restrict__ gidx,
                 const float* __restrict__ W0, int b, int m0, int t,
                 float* xs, float* w0sT, uint32_t* s_gi, float* s_qc) {
  for (int i = t; i < 64 * 67; i += 256) {
    int o = i / 67, c = i - o * 67;
    w0sT[c * WST + o] = W0[i];
  }
  if (t < 128) {
    s_gi[t] = gidx[((size_t)(b * Mn + m0)) * 32 + t];
  } else if (t < 132) {
    int mm = t - 128;
    uint32_t si = sidx[b * Mn + m0 + mm];
    const float* c = &coords[((size_t)b * Nn + si) * 3];
    s_qc[mm * 3 + 0] = c[0]; s_qc[mm * 3 + 1] = c[1]; s_qc[mm * 3 + 2] = c[2];
  }
  __syncthreads();
  if (t < 128) {
    int mm = t >> 5;
    const float* c = &coords[((size_t)b * Nn + s_gi[t]) * 3];
    xs[0 * XST + t] = (c[0] - s_qc[mm * 3 + 0]) / 0.2f;
    xs[1 * XST + t] = (c[1] - s_qc[mm * 3 + 1]) / 0.2f;
    xs[2 * XST + t] = (c[2] - s_qc[mm * 3 + 2]) / 0.2f;
  }
  {
    int c = t & 63, k0g = t >> 6;
    for (int r2 = 0; r2 < 32; ++r2) {
      int kk = k0g + 4 * r2;
      xs[(size_t)(3 + c) * XST + kk] = featsT[((size_t)b * Nn + s_gi[kk]) * 64 + c];
    }
  }
  __syncthreads();
}

DEV void conv1_acc(const float* xs, const float* w0sT, int o0, int k0, float acc[32]) {
#pragma unroll
  for (int i = 0; i < 32; ++i) acc[i] = 0.f;
  for (int c = 0; c < 67; ++c) {
    float4 w  = *(const float4*)&w0sT[c * WST + o0];
    float4 xa = *(const float4*)&xs[c * XST + k0];
    float4 xb = *(const float4*)&xs[c * XST + k0 + 4];
    float wv[4] = {w.x, w.y, w.z, w.w};
    float xv[8] = {xa.x, xa.y, xa.z, xa.w, xb.x, xb.y, xb.z, xb.w};
#pragma unroll
    for (int i = 0; i < 4; ++i)
#pragma unroll
      for (int j = 0; j < 8; ++j)
        acc[i * 8 + j] = fmaf(wv[i], xv[j], acc[i * 8 + j]);
  }
}

DEV void conv2_acc(const float* hs, const float* w1sT, int o0, int k0, float acc2[32]) {
#pragma unroll
  for (int i = 0; i < 32; ++i) acc2[i] = 0.f;
  for (int c = 0; c < 64; ++c) {
    float4 w  = *(const float4*)&w1sT[c * WST + o0];
    float4 xa = *(const float4*)&hs[c * XST + k0];
    float4 xb = *(const float4*)&hs[c * XST + k0 + 4];
    float wv[4] = {w.x, w.y, w.z, w.w};
    float xv[8] = {xa.x, xa.y, xa.z, xa.w, xb.x, xb.y, xb.z, xb.w};
#pragma unroll
    for (int i = 0; i < 4; ++i)
#pragma unroll
      for (int j = 0; j < 8; ++j)
        acc2[i * 8 + j] = fmaf(wv[i], xv[j], acc2[i * 8 + j]);
  }
}

// stats layout (floats): [0,64) s0 | [64,128) q0 | [128,256) s1 | [256,384) q1
// | [384,512) ss | [512,640) qs | 640 a0 | 704 c0 | 768 a1 | 896 c1
// | 1024 as | 1152 cs
__global__ __launch_bounds__(256) void k_conv1(const float* __restrict__ coords,
                                               const float* __restrict__ featsT,
                                               const uint32_t* __restrict__ sidx,
                                               const uint32_t* __restrict__ gidx,
                                               const float* __restrict__ W0,
                                               float* __restrict__ stats) {
  __shared__ float xs[67 * XST];
  __shared__ float w0sT[67 * WST];
  __shared__ uint32_t s_gi[128];
  __shared__ float s_qc[12];
  __shared__ float ssum[64], ssq[64];
  int blk = blockIdx.x, t = threadIdx.x;
  int b = blk >> 8, m0 = (blk & 255) << 2;
  if (t < 64) { ssum[t] = 0.f; ssq[t] = 0.f; }
  build_x(coords, featsT, sidx, gidx, W0, b, m0, t, xs, w0sT, s_gi, s_qc);
  int o0 = (t & 15) * 4, k0 = (t >> 4) * 8;
  float acc[32];
  conv1_acc(xs, w0sT, o0, k0, acc);
#pragma unroll
  for (int i = 0; i < 4; ++i) {
    float s = 0.f, sq = 0.f;
#pragma unroll
    for (int j = 0; j < 8; ++j) { s += acc[i * 8 + j]; sq = fmaf(acc[i * 8 + j], acc[i * 8 + j], sq); }
    atomicAdd(&ssum[o0 + i], s); atomicAdd(&ssq[o0 + i], sq);
  }
  __syncthreads();
  if (t < 64) { atomicAdd(&stats[t], ssum[t]); atomicAdd(&stats[64 + t], ssq[t]); }
}

__global__ void k_fin0(float* stats, const float* g0, const float* b0) {
  int t = threadIdx.x;
  if (t >= 64) return;
  float mu  = stats[t] * (1.f / 262144.f);
  float var = stats[64 + t] * (1.f / 262144.f) - mu * mu;
  float a = g0[t] / sqrtf(var + 1e-5f);
  stats[640 + t] = a;
  stats[704 + t] = b0[t] - mu * a;
}

__global__ __launch_bounds__(256) void k_conv2(const float* __restrict__ coords,
                                               const float* __restrict__ featsT,
                                               const uint32_t* __restrict__ sidx,
                                               const uint32_t* __restrict__ gidx,
                                               const float* __restrict__ W0,
                                               const float* __restrict__ W1,
                                               float* __restrict__ stats) {
  __shared__ float smU[13400];  // xs+w0sT (8844+4556) | hs+w1sT (8448+4352)
  __shared__ uint32_t s_gi[128];
  __shared__ float s_qc[12];
  __shared__ float ssum[128], ssq[128];
  float* xs = smU;  float* w0sT = smU + 67 * XST;
  float* hs = smU;  float* w1sT = smU + 64 * XST;
  int blk = blockIdx.x, t = threadIdx.x;
  int b = blk >> 8, m0 = (blk & 255) << 2;
  if (t < 128) { ssum[t] = 0.f; ssq[t] = 0.f; }
  build_x(coords, featsT, sidx, gidx, W0, b, m0, t, xs, w0sT, s_gi, s_qc);
  int o0 = (t & 15) * 4, k0 = (t >> 4) * 8;
  float acc[32];
  conv1_acc(xs, w0sT, o0, k0, acc);
  float4 a04 = *(const float4*)&stats[640 + o0];
  float4 c04 = *(const float4*)&stats[704 + o0];
  float a0v[4] = {a04.x, a04.y, a04.z, a04.w};
  float c0v[4] = {c04.x, c04.y, c04.z, c04.w};
  __syncthreads();  // all conv1 LDS reads complete; smU repurposed
#pragma unroll
  for (int i = 0; i < 4; ++i) {
    float h[8];
#pragma unroll
    for (int j = 0; j < 8; ++j) h[j] = fmaxf(fmaf(a0v[i], acc[i * 8 + j], c0v[i]), 0.f);
    *(float4*)&hs[(o0 + i) * XST + k0]     = make_float4(h[0], h[1], h[2], h[3]);
    *(float4*)&hs[(o0 + i) * XST + k0 + 4] = make_float4(h[4], h[5], h[6], h[7]);
  }
  for (int p = 0; p < 2; ++p) {
    __syncthreads();
    for (int i = t; i < 64 * 64; i += 256) {
      int oo = i >> 6, cc = i & 63;
      w1sT[cc * WST + oo] = W1[(size_t)(64 * p + oo) * 64 + cc];
    }
    __syncthreads();
    float acc2[32];
    conv2_acc(hs, w1sT, o0, k0, acc2);
#pragma unroll
    for (int i = 0; i < 4; ++i) {
      float s = 0.f, sq = 0.f;
#pragma unroll
      for (int j = 0; j < 8; ++j) { s += acc2[i * 8 + j]; sq = fmaf(acc2[i * 8 + j], acc2[i * 8 + j], sq); }
      atomicAdd(&ssum[64 * p + o0 + i], s); atomicAdd(&ssq[64 * p + o0 + i], sq);
    }
  }
  __syncthreads();
  if (t < 128) { atomicAdd(&stats[128 + t], ssum[t]); atomicAdd(&stats[256 + t], ssq[t]); }
}

__global__ __launch_bounds__(256) void k_skip(const float* __restrict__ featsT,
                                              const uint32_t* __restrict__ sidx,
                                              const float* __restrict__ Ws,
                                              float* __restrict__ ys,
                                              float* __restrict__ stats) {
  __shared__ float fin[64 * 65];
  __shared__ float wssT[64 * 129];
  __shared__ uint32_t s_si[64];
  __shared__ float ssum[128], ssq[128];
  int blk = blockIdx.x, t = threadIdx.x;
  int b = blk >> 4, m0 = (blk & 15) * 64;
  if (t < 64) s_si[t] = sidx[b * Mn + m0 + t];
  if (t < 128) { ssum[t] = 0.f; ssq[t] = 0.f; }
  __syncthreads();
  for (int i = t; i < 64 * 64; i += 256) {
    int mm = i >> 6, c = i & 63;
    fin[mm * 65 + c] = featsT[((size_t)b * Nn + s_si[mm]) * 64 + c];
  }
  for (int i = t; i < 128 * 64; i += 256) {
    int oo = i >> 6, cc = i & 63;
    wssT[cc * 129 + oo] = Ws[(size_t)oo * 64 + cc];
  }
  __syncthreads();
  int o = t & 127, mh = t >> 7;
  float s = 0.f, sq = 0.f;
  for (int mm = mh * 32; mm < mh * 32 + 32; ++mm) {
    float acc = 0.f;
    for (int c = 0; c < 64; ++c) acc = fmaf(wssT[c * 129 + o], fin[mm * 65 + c], acc);
    ys[((size_t)(b * Mn + m0 + mm)) * 128 + o] = acc;
    s += acc; sq = fmaf(acc, acc, sq);
  }
  atomicAdd(&ssum[o], s); atomicAdd(&ssq[o], sq);
  __syncthreads();
  if (t < 128) { atomicAdd(&stats[384 + t], ssum[t]); atomicAdd(&stats[512 + t], ssq[t]); }
}

__global__ void k_fin1(float* stats, const float* g1, const float* b1,
                       const float* gs, const float* bs) {
  int t = threadIdx.x;
  if (t >= 128) return;
  float mu  = stats[128 + t] * (1.f / 262144.f);
  float var = stats[256 + t] * (1.f / 262144.f) - mu * mu;
  float a = g1[t] / sqrtf(var + 1e-5f);
  stats[768 + t] = a;
  stats[896 + t] = b1[t] - mu * a;
  float mus  = stats[384 + t] * (1.f / 8192.f);
  float vars = stats[512 + t] * (1.f / 8192.f) - mus * mus;
  float as = gs[t] / sqrtf(vars + 1e-5f);
  stats[1024 + t] = as;
  stats[1152 + t] = bs[t] - mus * as;
}

__global__ __launch_bounds__(256) void k_out(const float* __restrict__ coords,
                                             const float* __restrict__ featsT,
                                             const uint32_t* __restrict__ sidx,
                                             const uint32_t* __restrict__ gidx,
                                             const float* __restrict__ W0,
                                             const float* __restrict__ W1,
                                             const float* __restrict__ wts,
                                             const float* __restrict__ ys,
                                             const float* __restrict__ stats,
                                             float* __restrict__ out_feat) {
  __shared__ float smU[13400];
  __shared__ uint32_t s_gi[128];
  __shared__ float s_qc[12];
  __shared__ float sw[4 * 36];
  __shared__ float red[128 * 5];
  float* xs = smU;  float* w0sT = smU + 67 * XST;
  float* hs = smU;  float* w1sT = smU + 64 * XST;
  int blk = blockIdx.x, t = threadIdx.x;
  int b = blk >> 8, m0 = (blk & 255) << 2;
  build_x(coords, featsT, sidx, gidx, W0, b, m0, t, xs, w0sT, s_gi, s_qc);
  if (t < 128) sw[(t >> 5) * 36 + (t & 31)] = wts[((size_t)(b * Mn + m0)) * 32 + t];
  int o0 = (t & 15) * 4, k0 = (t >> 4) * 8;
  int m = k0 >> 5, nb0 = k0 & 31;  // query idx (== wave id), neighbor offset
  float acc[32];
  conv1_acc(xs, w0sT, o0, k0, acc);
  float4 a04 = *(const float4*)&stats[640 + o0];
  float4 c04 = *(const float4*)&stats[704 + o0];
  float a0v[4] = {a04.x, a04.y, a04.z, a04.w};
  float c0v[4] = {c04.x, c04.y, c04.z, c04.w};
  __syncthreads();
#pragma unroll
  for (int i = 0; i < 4; ++i) {
    float h[8];
#pragma unroll
    for (int j = 0; j < 8; ++j) h[j] = fmaxf(fmaf(a0v[i], acc[i * 8 + j], c0v[i]), 0.f);
    *(float4*)&hs[(o0 + i) * XST + k0]     = make_float4(h[0], h[1], h[2], h[3]);
    *(float4*)&hs[(o0 + i) * XST + k0 + 4] = make_float4(h[4], h[5], h[6], h[7]);
  }
  for (int p = 0; p < 2; ++p) {
    __syncthreads();
    for (int i = t; i < 64 * 64; i += 256) {
      int oo = i >> 6, cc = i & 63;
      w1sT[cc * WST + oo] = W1[(size_t)(64 * p + oo) * 64 + cc];
    }
    __syncthreads();
    float acc2[32];
    conv2_acc(hs, w1sT, o0, k0, acc2);
    float4 swa = *(const float4*)&sw[m * 36 + nb0];
    float4 swb = *(const float4*)&sw[m * 36 + nb0 + 4];
    float wv[8] = {swa.x, swa.y, swa.z, swa.w, swb.x, swb.y, swb.z, swb.w};
    float4 a14 = *(const float4*)&stats[768 + 64 * p + o0];
    float4 c14 = *(const float4*)&stats[896 + 64 * p + o0];
    float a1v[4] = {a14.x, a14.y, a14.z, a14.w};
    float c1v[4] = {c14.x, c14.y, c14.z, c14.w};
    float r4[4];
#pragma unroll
    for (int i = 0; i < 4; ++i) {
      float r = 0.f;
#pragma unroll
      for (int j = 0; j < 8; ++j) {
        float msg = fmaxf(fmaf(a1v[i], acc2[i * 8 + j], c1v[i]), 0.f);
        r = fmaf(msg, wv[j], r);
      }
      r4[i] = r;
    }
#pragma unroll
    for (int i = 0; i < 4; ++i) {  // sum the 4 neighbor-subgroups (lane strides 16,32)
      float r = r4[i];
      r += __shfl_xor(r, 16, 64);
      r += __shfl_xor(r, 32, 64);
      r4[i] = r;
    }
    if ((t & 63) < 16) {
      float4 ysv = *(const float4*)&ys[((size_t)(b * Mn + m0 + m)) * 128 + 64 * p + o0];
      float4 as4 = *(const float4*)&stats[1024 + 64 * p + o0];
      float4 cs4 = *(const float4*)&stats[1152 + 64 * p + o0];
      float yv[4] = {ysv.x, ysv.y, ysv.z, ysv.w};
      float av[4] = {as4.x, as4.y, as4.z, as4.w};
      float cv[4] = {cs4.x, cs4.y, cs4.z, cs4.w};
#pragma unroll
      for (int i = 0; i < 4; ++i)
        red[(64 * p + o0 + i) * 5 + m] = fmaxf(r4[i] + fmaf(av[i], yv[i], cv[i]), 0.f);
    }
  }
  __syncthreads();
  for (int e = t; e < 512; e += 256) {
    int oo = e >> 2, mm = e & 3;
    out_feat[(size_t)b * 131072 + (size_t)oo * 1024 + m0 + mm] = red[oo * 5 + mm];
  }
}

// ---------------------------------------------------------------------------
extern "C" void kernel_launch(void* const* d_in, const int* in_sizes, int n_in,
                              void* d_out, int out_size, void* d_ws, size_t ws_size,
                              hipStream_t stream) {
  const float* coords = (const float*)d_in[0];
  const float* feats  = (const float*)d_in[1];
  const float* W0 = (const float*)d_in[2];
  const float* g0 = (const float*)d_in[3];
  const float* b0 = (const float*)d_in[4];
  const float* W1 = (const float*)d_in[5];
  const float* g1 = (const float*)d_in[6];
  const float* b1 = (const float*)d_in[7];
  const float* Ws = (const float*)d_in[8];
  const float* gs = (const float*)d_in[9];
  const float* bs = (const float*)d_in[10];

  float* out_coords = (float*)d_out;
  float* out_feat   = out_coords + (size_t)Bn * Mn * 3;

  char* w = (char*)d_ws;
  float*    featsT = (float*)w;    w += (size_t)Bn * Nn * CIN * 4;   // 8 MB
  uint32_t* sidx   = (uint32_t*)w; w += (size_t)Bn * Mn * 4;
  uint32_t* gidx   = (uint32_t*)w; w += (size_t)Bn * Mn * Kn * 4;
  float*    wts    = (float*)w;    w += (size_t)Bn * Mn * Kn * 4;
  float*    ys     = (float*)w;    w += (size_t)Bn * Mn * COUT * 4;  // 4 MB
  float*    stats  = (float*)w;    w += 1280 * 4;

  hipMemsetAsync(stats, 0, 640 * 4, stream);
  hipLaunchKernelGGL(k_tr,    dim3(512),  dim3(256), 0, stream, feats, featsT);
  hipLaunchKernelGGL(k_fps,   dim3(8),    dim3(256), 0, stream, coords, sidx, out_coords);
  hipLaunchKernelGGL(k_knn,   dim3(8192), dim3(256), 0, stream, coords, sidx, gidx, wts);
  hipLaunchKernelGGL(k_conv1, dim3(2048), dim3(256), 0, stream, coords, featsT, sidx, gidx, W0, stats);
  hipLaunchKernelGGL(k_skip,  dim3(128),  dim3(256), 0, stream, featsT, sidx, Ws, ys, stats);
  hipLaunchKernelGGL(k_fin0,  dim3(1),    dim3(64),  0, stream, stats, g0, b0);
  hipLaunchKernelGGL(k_conv2, dim3(2048), dim3(256), 0, stream, coords, featsT, sidx, gidx, W0, W1, stats);
  hipLaunchKernelGGL(k_fin1,  dim3(1),    dim3(128), 0, stream, stats, g1, b1, gs, bs);
  hipLaunchKernelGGL(k_out,   dim3(2048), dim3(256), 0, stream, coords, featsT, sidx, gidx, W0, W1, wts, ys, stats, out_feat);
}